// Round 12
// baseline (316.539 us; speedup 1.0000x reference)
//
#include <hip/hip_runtime.h>
#include <hip/hip_bf16.h>
#include <cstdint>

#define TOKENS 8192
#define IN_F   4096
#define OUT_F  4096

#define BM 256
#define BN 256
#define BK 64
#define NT (IN_F / BK)   // 64 K-tiles
#define THREADS 512

typedef __attribute__((ext_vector_type(8))) short bf16x8;
typedef __attribute__((ext_vector_type(4))) float f32x4;

#define GLOBAL_AS __attribute__((address_space(1)))
#define LDS_AS    __attribute__((address_space(3)))

#define BARRIER() __builtin_amdgcn_s_barrier()
#define LGKM(n)   do { asm volatile("s_waitcnt lgkmcnt(" #n ")"); \
                       __builtin_amdgcn_sched_barrier(0); } while (0)
#define VMCNT(n)  do { asm volatile("s_waitcnt vmcnt(" #n ")"); \
                       __builtin_amdgcn_sched_barrier(0); } while (0)

__device__ __forceinline__ unsigned short f2bf(float f) {
  union { float f; unsigned int u; } v;
  v.f = f;
  unsigned int r = 0x7FFFu + ((v.u >> 16) & 1u);
  return (unsigned short)((v.u + r) >> 16);
}

__device__ __forceinline__ float softplus_f(float x) {
  return log1pf(expf(x));
}

// ---------------- fused prep kernel ----------------

#define NW4 ((long long)OUT_F * IN_F / 4)
#define NX4 ((long long)TOKENS * IN_F / 4)
#define NB4 (OUT_F / 4)

__global__ void prep_kernel(const float* __restrict__ x,
                            const float* __restrict__ wmu,
                            const float* __restrict__ wrho,
                            const float* __restrict__ weps,
                            const float* __restrict__ bmu,
                            const float* __restrict__ brho,
                            const float* __restrict__ beps,
                            unsigned short* __restrict__ xb,
                            unsigned short* __restrict__ wb,
                            float* __restrict__ bias) {
  long long i = (long long)blockIdx.x * blockDim.x + threadIdx.x;
  long long stride = (long long)gridDim.x * blockDim.x;
  const long long total = NW4 + NX4 + NB4;
  for (; i < total; i += stride) {
    if (i < NW4) {
      float4 m = reinterpret_cast<const float4*>(wmu)[i];
      float4 r = reinterpret_cast<const float4*>(wrho)[i];
      float4 e = reinterpret_cast<const float4*>(weps)[i];
      ushort4 o;
      o.x = f2bf(fmaf(softplus_f(r.x), e.x, m.x));
      o.y = f2bf(fmaf(softplus_f(r.y), e.y, m.y));
      o.z = f2bf(fmaf(softplus_f(r.z), e.z, m.z));
      o.w = f2bf(fmaf(softplus_f(r.w), e.w, m.w));
      reinterpret_cast<ushort4*>(wb)[i] = o;
    } else if (i < NW4 + NX4) {
      long long j = i - NW4;
      float4 m = reinterpret_cast<const float4*>(x)[j];
      ushort4 o;
      o.x = f2bf(m.x); o.y = f2bf(m.y); o.z = f2bf(m.z); o.w = f2bf(m.w);
      reinterpret_cast<ushort4*>(xb)[j] = o;
    } else {
      long long j = i - NW4 - NX4;
      float4 m = reinterpret_cast<const float4*>(bmu)[j];
      float4 r = reinterpret_cast<const float4*>(brho)[j];
      float4 e = reinterpret_cast<const float4*>(beps)[j];
      float4 o;
      o.x = fmaf(softplus_f(r.x), e.x, m.x);
      o.y = fmaf(softplus_f(r.y), e.y, m.y);
      o.z = fmaf(softplus_f(r.z), e.z, m.z);
      o.w = fmaf(softplus_f(r.w), e.w, m.w);
      reinterpret_cast<float4*>(bias)[j] = o;
    }
  }
}

// ---------------- GEMM: 256x256, full-tile register prefetch ----------------
// r12: every ds_read fetches NEXT work (next quadrant / next tile) while MFMAs
// consume current regs — no lgkm dependency inside any MFMA window (r4-r11 all
// serialized read-burst -> MFMA-burst; model: 576+620 cyc/phase = measured).
// Per tile: publish(t+1) [VMCNT(0)+bar, free]; lgkm(0)+bar2 [closes B-slot
// write race]; stage(t+2); 4 phases of {16 MFMA || 4 A-reads + 2 B-reads,
// LGKM(2) counted}. B dbuf per tile (bvA/bvB), A ping-pong per phase (avA/avB,
// statically unrolled — rule 20). acc 128 + bv 64 + av 32 regs -> <=256,
// 2 waves/SIMD (launch_bounds(512,2)).
// Hazards: A-slot (t+2)%3 readers drained a full tile before bar2; B-slot
// (t+2)&1 = t&1 readers (bv(t), read during t-1) drained by lgkm(0) before
// bar2(t) < stage. vmcnt: VMCNT(0) at top drains stage(t+1) issued ~2400 cyc
// ago (free). Tail: t+1>=NT -> skip next reads, LGKM(2)->LGKM(0).
// LDS swizzle: chunk ^= (row & 7) via pre-swizzled global source (linear
// global_load_lds dest) + matching XOR on ds_read (rule 21 involution).

__global__ __launch_bounds__(THREADS, 2) void gemm_bt_kernel(
    const unsigned short* __restrict__ A,   // [TOKENS][IN_F] bf16
    const unsigned short* __restrict__ B,   // [OUT_F][IN_F] bf16
    const float* __restrict__ bias,         // [OUT_F]
    float* __restrict__ C)                  // [TOKENS][OUT_F]
{
  __shared__ unsigned short lds[5 * 16384]; // A slots @0,16384,32768; B @49152,65536

  const int tid  = threadIdx.x;
  const int lane = tid & 63;
  const int wave = tid >> 6;   // 0..7
  const int wm   = wave >> 2;  // 0..1
  const int wn   = wave & 3;   // 0..3

  // XCD-aware bijective block swizzle (512 = 8 XCD chunks x 64)
  const int bid = blockIdx.x;
  const int wg  = (bid & 7) * 64 + (bid >> 3);
  const int ch  = wg >> 6;
  const int idx = wg & 63;
  const int bm  = (ch >> 1) * 8 + (idx >> 3);  // 0..31
  const int bn  = (ch & 1) * 8 + (idx & 7);    // 0..15

  const int lane15 = lane & 15;
  const int cgrp   = lane >> 4;                // 0..3
  const int rdoff0 = lane15 * 64 + ((cgrp ^ (lane & 7)) * 8);
  const int rdoff1 = lane15 * 64 + (((4 + cgrp) ^ (lane & 7)) * 8);

  // staging: per-lane pre-swizzled global source; each wave stages 32 rows
  const int srow = lane >> 3;                  // 0..7
  const int scol = ((lane & 7) ^ srow) * 8;    // swizzled 16B chunk -> elems
  const unsigned short* Asrc = A + (size_t)(bm * BM + wave * 32 + srow) * IN_F + scol;
  const unsigned short* Bsrc = B + (size_t)(bn * BN + wave * 32 + srow) * IN_F + scol;

  f32x4 acc[8][4] = {};
  bf16x8 bvA[4][2], bvB[4][2], avA[2][2], avB[2][2];

  auto stA4 = [&](int slot, int t) {
    unsigned short* dst = &lds[slot * 16384 + wave * 2048];
    const unsigned short* g = Asrc + t * BK;
#pragma unroll
    for (int i = 0; i < 4; ++i)
      __builtin_amdgcn_global_load_lds((const GLOBAL_AS void*)(g + (size_t)(i * 8) * IN_F),
                                       (LDS_AS void*)(dst + i * 512), 16, 0, 0);
  };
  auto stB4 = [&](int slot, int t) {
    unsigned short* dst = &lds[49152 + slot * 16384 + wave * 2048];
    const unsigned short* g = Bsrc + t * BK;
#pragma unroll
    for (int i = 0; i < 4; ++i)
      __builtin_amdgcn_global_load_lds((const GLOBAL_AS void*)(g + (size_t)(i * 8) * IN_F),
                                       (LDS_AS void*)(dst + i * 512), 16, 0, 0);
  };

  auto rdA4 = [&](const unsigned short* Ar, int q, bf16x8 (&av)[2][2]) {
#pragma unroll
    for (int f = 0; f < 2; ++f) {
      const unsigned short* p = Ar + (wm * 128 + q * 32 + f * 16) * 64;
      av[f][0] = *reinterpret_cast<const bf16x8*>(p + rdoff0);
      av[f][1] = *reinterpret_cast<const bf16x8*>(p + rdoff1);
    }
  };
  auto rdB2 = [&](const unsigned short* Br, int n, bf16x8 (&bv)[4][2]) {
    const unsigned short* p = Br + (wn * 64 + n * 16) * 64;
    bv[n][0] = *reinterpret_cast<const bf16x8*>(p + rdoff0);
    bv[n][1] = *reinterpret_cast<const bf16x8*>(p + rdoff1);
  };
  auto mfma16 = [&](bf16x8 (&av)[2][2], bf16x8 (&bv)[4][2], f32x4* r0, f32x4* r1) {
    __builtin_amdgcn_s_setprio(1);
#pragma unroll
    for (int kk = 0; kk < 2; ++kk) {
#pragma unroll
      for (int n = 0; n < 4; ++n) {
        r0[n] = __builtin_amdgcn_mfma_f32_16x16x32_bf16(av[0][kk], bv[n][kk], r0[n], 0, 0, 0);
        r1[n] = __builtin_amdgcn_mfma_f32_16x16x32_bf16(av[1][kk], bv[n][kk], r1[n], 0, 0, 0);
      }
    }
    __builtin_amdgcn_s_setprio(0);
  };

  // prologue: stage t0 (slots A0,B0) + t1 (A1,B1); wait t0; preload t0 frags
  stA4(0, 0); stB4(0, 0);
  stA4(1, 1); stB4(1, 1);
  VMCNT(8);
  BARRIER();
#pragma unroll
  for (int n = 0; n < 4; ++n) rdB2(&lds[49152], n, bvA);
  rdA4(&lds[0], 0, avA);

  // per-tile body; bvc = current tile's B (in regs), bva = buffer for t+1's B
  auto tile_body = [&](int t, const unsigned short* AsC, const unsigned short* AsN,
                       const unsigned short* BsN, int a2, int b2,
                       bf16x8 (&bvc)[4][2], bf16x8 (&bva)[4][2]) {
    const bool nx = (t + 1 < NT);
    const bool pf = (t + 2 < NT);

    VMCNT(0);        // stage(t+1) landed (issued ~1 tile ago)
    BARRIER();       // publish t+1
    LGKM(0);         // all own reads of frags(<=t) drained (long ago)
    BARRIER();       // bar2: globally safe to overwrite B-slot t&1 / A-slot (t+2)%3
    if (pf) { stA4(a2, t + 2); stB4(b2, t + 2); }

    // ph q0: MFMA on avA/bvc; read av(q1)->avB, bv(t+1)[0]->bva
    mfma16(avA, bvc, acc[0], acc[1]);
    rdA4(AsC, 1, avB);
    if (nx) { rdB2(BsN, 0, bva); LGKM(2); } else { LGKM(0); }

    // ph q1
    mfma16(avB, bvc, acc[2], acc[3]);
    rdA4(AsC, 2, avA);
    if (nx) { rdB2(BsN, 1, bva); LGKM(2); } else { LGKM(0); }

    // ph q2
    mfma16(avA, bvc, acc[4], acc[5]);
    rdA4(AsC, 3, avB);
    if (nx) { rdB2(BsN, 2, bva); LGKM(2); } else { LGKM(0); }

    // ph q3: read av(q0,t+1) from next A slot + last B pair
    mfma16(avB, bvc, acc[6], acc[7]);
    if (nx) { rdA4(AsN, 0, avA); rdB2(BsN, 3, bva); }
  };

  int a0 = 0, a1 = 1, a2 = 2;   // A slots for tiles t, t+1, t+2
  for (int t = 0; t < NT; t += 2) {
    // even tile: B cur slot t&1=0 is in bvA; next B (t+1) in slot 1
    tile_body(t,     &lds[a0 * 16384], &lds[a1 * 16384],
              &lds[49152 + 16384], a2, 0, bvA, bvB);
    // odd tile
    tile_body(t + 1, &lds[a1 * 16384], &lds[a2 * 16384],
              &lds[49152],          a0, 1, bvB, bvA);
    int na0 = a2, na1 = a0, na2 = a1;   // rotate by 2 tiles
    a0 = na0; a1 = na1; a2 = na2;
  }

  // epilogue: C/D layout col=lane&15, row=(lane>>4)*4+reg
  const int colg0 = bn * BN + wn * 64 + lane15;
  const int rowg0 = bm * BM + wm * 128 + (lane >> 4) * 4;
#pragma unroll
  for (int ni = 0; ni < 4; ++ni) {
    const int colg = colg0 + ni * 16;
    const float bvs = bias[colg];
#pragma unroll
    for (int mi = 0; mi < 8; ++mi) {
      const int rowg = rowg0 + mi * 16;
#pragma unroll
      for (int r = 0; r < 4; ++r)
        C[(size_t)(rowg + r) * OUT_F + colg] = acc[mi][ni][r] + bvs;
    }
  }
}

// ---------------- fallback (only if ws too small) ----------------

__global__ void fallback_kernel(const float* __restrict__ x,
                                const float* __restrict__ wmu,
                                const float* __restrict__ wrho,
                                const float* __restrict__ weps,
                                const float* __restrict__ bmu,
                                const float* __restrict__ brho,
                                const float* __restrict__ beps,
                                float* __restrict__ out) {
  int o = blockIdx.x * blockDim.x + threadIdx.x;
  int t = blockIdx.y;
  float s = 0.f;
  const float* xr = x + (size_t)t * IN_F;
  const float* wm = wmu + (size_t)o * IN_F;
  const float* wr = wrho + (size_t)o * IN_F;
  const float* we = weps + (size_t)o * IN_F;
  for (int k = 0; k < IN_F; ++k)
    s += xr[k] * fmaf(softplus_f(wr[k]), we[k], wm[k]);
  out[(size_t)t * OUT_F + o] = s + fmaf(softplus_f(brho[o]), beps[o], bmu[o]);
}

// ---------------- launch ----------------

extern "C" void kernel_launch(void* const* d_in, const int* in_sizes, int n_in,
                              void* d_out, int out_size, void* d_ws, size_t ws_size,
                              hipStream_t stream) {
  const float* x    = (const float*)d_in[0];
  const float* wmu  = (const float*)d_in[1];
  const float* wrho = (const float*)d_in[2];
  const float* bmu  = (const float*)d_in[3];
  const float* brho = (const float*)d_in[4];
  const float* weps = (const float*)d_in[5];
  const float* beps = (const float*)d_in[6];
  float* out = (float*)d_out;

  const size_t xb_off   = 0;
  const size_t wb_off   = (size_t)TOKENS * IN_F * 2;            // 64 MB
  const size_t bias_off = wb_off + (size_t)OUT_F * IN_F * 2;    // +32 MB
  const size_t needed   = bias_off + (size_t)OUT_F * 4;

  if (ws_size < needed) {
    dim3 g(OUT_F / 256, TOKENS);
    hipLaunchKernelGGL(fallback_kernel, g, dim3(256), 0, stream,
                       x, wmu, wrho, weps, bmu, brho, beps, out);
    return;
  }

  unsigned short* xb = (unsigned short*)((char*)d_ws + xb_off);
  unsigned short* wb = (unsigned short*)((char*)d_ws + wb_off);
  float* bias = (float*)((char*)d_ws + bias_off);

  hipLaunchKernelGGL(prep_kernel, dim3(2048), dim3(256), 0, stream,
                     x, wmu, wrho, weps, bmu, brho, beps, xb, wb, bias);

  hipLaunchKernelGGL(gemm_bt_kernel,
                     dim3((TOKENS / BM) * (OUT_F / BN)), dim3(THREADS), 0, stream,
                     xb, wb, bias, out);
}